// Round 1
// baseline (1182.315 us; speedup 1.0000x reference)
//
#include <hip/hip_runtime.h>
#include <math.h>

// dims
#define BS 16
#define C_ 684
#define Hh 32
#define Ww 128
#define HW 4096
#define Qc 256
#define Kk 11
#define NP 512
#define Nn 256

// workspace layout (float offsets)
#define WS_BETA 0            // 16*4096      = 65536
#define WS_UAT  65536        // 684*512      = 350208
#define WS_W2T  415744       // 121*512      = 61952
#define WS_BIAS 477696       // 16*512       = 8192
#define WS_E    485888       // 16*4096      = 65536
// total 551424 floats = 2.2 MB

// ---- beta = sum_t alpha ------------------------------------------------
__global__ void k_beta(const float* __restrict__ alpha, float* __restrict__ beta) {
    int idx = blockIdx.x * 256 + threadIdx.x;            // 65536
    int b = idx >> 12, n = idx & 4095;
    const float* a = alpha + (size_t)b * 4 * HW + n;
    beta[idx] = a[0] + a[HW] + a[2 * HW] + a[3 * HW];
}

// ---- UaT[c][p] = convUa_w[p][c] ---------------------------------------
__global__ void k_uat(const float* __restrict__ ua, float* __restrict__ uat) {
    int idx = blockIdx.x * 256 + threadIdx.x;
    if (idx >= C_ * NP) return;
    int c = idx >> 9, p = idx & 511;
    uat[idx] = ua[p * C_ + c];
}

// ---- W2T[tap][p] = sum_q Uf_w[p][q] * convQ_w[q][tap] ------------------
__global__ void k_w2t(const float* __restrict__ ufw, const float* __restrict__ qw,
                      float* __restrict__ w2t) {
    int idx = blockIdx.x * 256 + threadIdx.x;            // 121*512
    if (idx >= 121 * NP) return;
    int tap = idx >> 9, p = idx & 511;
    float s = 0.f;
    for (int q = 0; q < Qc; ++q) s += ufw[p * Qc + q] * qw[q * 121 + tap];
    w2t[idx] = s;
}

// ---- Bias[b][p] = query + Wa_b + Uf_b + Uf_w@convQ_b + convUa_b --------
__global__ void k_bias(const float* __restrict__ st, const float* __restrict__ waw,
                       const float* __restrict__ wab, const float* __restrict__ ufw,
                       const float* __restrict__ ufb, const float* __restrict__ qb,
                       const float* __restrict__ uab, float* __restrict__ bias) {
    int idx = blockIdx.x * 256 + threadIdx.x;            // 8192
    int b = idx >> 9, p = idx & 511;
    float s = wab[p] + ufb[p] + uab[p];
    const float* sv = st + b * Nn;
    const float* wr = waw + p * Nn;
    for (int n = 0; n < Nn; ++n) s += sv[n] * wr[n];
    const float* ur = ufw + p * Qc;
    for (int q = 0; q < Qc; ++q) s += ur[q] * qb[q];
    bias[idx] = s;
}

// ---- fused score kernel: e[b][hw] --------------------------------------
// block = (batch, 16-pixel tile), 256 threads = 4 waves.
// wave lane = p-group (8 p's), wave id = pixel quad (4 pixels).
__launch_bounds__(256, 1)
__global__ void k_score(const float* __restrict__ x, const float* __restrict__ beta,
                        const float* __restrict__ uat, const float* __restrict__ w2t,
                        const float* __restrict__ bias, const float* __restrict__ vaw,
                        const float* __restrict__ vab, float* __restrict__ e) {
    __shared__ float xs[C_][16];     // 43776 B
    __shared__ float bp[Kk][28];     // 11 rows x 26 cols used

    const int tid = threadIdx.x;
    const int b = blockIdx.y;
    const int hw0 = blockIdx.x * 16;
    const int r = hw0 >> 7, c0 = hw0 & 127;

    // stage x tile: 684 channels x 16 pixels
    const float* xb = x + (size_t)b * C_ * HW + hw0;
    for (int idx = tid; idx < C_ * 4; idx += 256) {
        int c = idx >> 2, pq = idx & 3;
        *(float4*)&xs[c][pq * 4] = *(const float4*)(xb + (size_t)c * HW + pq * 4);
    }
    // stage beta patch: rows r-5..r+5, cols c0-5..c0+20
    if (tid < Kk * 26) {
        int di = tid / 26, k = tid % 26;
        int rr = r + di - 5, cc = c0 + k - 5;
        float v = 0.f;
        if (rr >= 0 && rr < Hh && cc >= 0 && cc < Ww) v = beta[b * HW + rr * 128 + cc];
        bp[di][k] = v;
    }
    __syncthreads();

    const int pg = tid & 63;       // lane = p-group
    const int pixq = tid >> 6;     // wave = pixel quad, uniform per wave
    const int p0 = pg * 8;
    const int po4 = p0 >> 2;

    float4 bb0 = *(const float4*)(bias + b * NP + p0);
    float4 bb1 = *(const float4*)(bias + b * NP + p0 + 4);
    float acc[8][4];
#pragma unroll
    for (int j = 0; j < 4; ++j) {
        acc[0][j] = bb0.x; acc[1][j] = bb0.y; acc[2][j] = bb0.z; acc[3][j] = bb0.w;
        acc[4][j] = bb1.x; acc[5][j] = bb1.y; acc[6][j] = bb1.z; acc[7][j] = bb1.w;
    }

    // key: sum_c UaT[c][p] * x[c][pix]
    const float4* uat4 = (const float4*)uat;
    for (int c = 0; c < C_; ++c) {
        float4 xv = *(const float4*)&xs[c][pixq * 4];
        float4 u0 = uat4[c * 128 + po4];
        float4 u1 = uat4[c * 128 + po4 + 1];
        float uu[8] = {u0.x, u0.y, u0.z, u0.w, u1.x, u1.y, u1.z, u1.w};
        float xx[4] = {xv.x, xv.y, xv.z, xv.w};
#pragma unroll
        for (int i = 0; i < 8; ++i)
#pragma unroll
            for (int j = 0; j < 4; ++j) acc[i][j] += uu[i] * xx[j];
    }

    // cover: 11x11 conv of beta with merged weights W2
    const float4* w2t4 = (const float4*)w2t;
    for (int di = 0; di < Kk; ++di) {
#pragma unroll 1
        for (int dj = 0; dj < Kk; ++dj) {
            int tap = di * Kk + dj;
            float4 w0 = w2t4[tap * 128 + po4];
            float4 w1 = w2t4[tap * 128 + po4 + 1];
            float ww[8] = {w0.x, w0.y, w0.z, w0.w, w1.x, w1.y, w1.z, w1.w};
            float bv[4];
#pragma unroll
            for (int j = 0; j < 4; ++j) bv[j] = bp[di][pixq * 4 + dj + j];
#pragma unroll
            for (int i = 0; i < 8; ++i)
#pragma unroll
                for (int j = 0; j < 4; ++j) acc[i][j] += ww[i] * bv[j];
        }
    }

    // e = Va . tanh(acc), reduce over p (across the 64 lanes)
    float4 v0 = *(const float4*)(vaw + p0);
    float4 v1 = *(const float4*)(vaw + p0 + 4);
    float vv[8] = {v0.x, v0.y, v0.z, v0.w, v1.x, v1.y, v1.z, v1.w};
    float es[4] = {0.f, 0.f, 0.f, 0.f};
#pragma unroll
    for (int i = 0; i < 8; ++i)
#pragma unroll
        for (int j = 0; j < 4; ++j) es[j] += vv[i] * tanhf(acc[i][j]);
#pragma unroll
    for (int off = 32; off > 0; off >>= 1) {
#pragma unroll
        for (int j = 0; j < 4; ++j) es[j] += __shfl_xor(es[j], off, 64);
    }
    if (pg == 0) {
        float vb = vab[0];
#pragma unroll
        for (int j = 0; j < 4; ++j) e[b * HW + hw0 + pixq * 4 + j] = es[j] + vb;
    }
}

// ---- softmax (reference form: exp / (sum + 1e-8), no max-subtract) -----
__global__ void k_softmax(const float* __restrict__ e, float* __restrict__ aout) {
    __shared__ float sred[256];
    int b = blockIdx.x, tid = threadIdx.x;
    float vloc[16];
    float ps = 0.f;
#pragma unroll
    for (int k = 0; k < 16; ++k) {
        float v = __expf(0.f); // placeholder avoided; real below
        (void)v;
        vloc[k] = expf(e[b * HW + tid + k * 256]);
        ps += vloc[k];
    }
    sred[tid] = ps;
    __syncthreads();
    for (int s = 128; s > 0; s >>= 1) {
        if (tid < s) sred[tid] += sred[tid + s];
        __syncthreads();
    }
    float scale = 1.f / (sred[0] + 1e-8f);
#pragma unroll
    for (int k = 0; k < 16; ++k) aout[b * HW + tid + k * 256] = vloc[k] * scale;
}

// ---- context[b][c] = sum_n alpha_t[b][n] * x[b][c][n] ------------------
__global__ void k_context(const float* __restrict__ x, const float* __restrict__ aout,
                          float* __restrict__ ctx) {
    __shared__ float sred[256];
    int c = blockIdx.x, b = blockIdx.y, tid = threadIdx.x;
    const float4* xr = (const float4*)(x + ((size_t)b * C_ + c) * HW);
    const float4* ar = (const float4*)(aout + b * HW);
    float acc = 0.f;
    for (int k = tid; k < 1024; k += 256) {
        float4 xv = xr[k], av = ar[k];
        acc += xv.x * av.x + xv.y * av.y + xv.z * av.z + xv.w * av.w;
    }
    sred[tid] = acc;
    __syncthreads();
    for (int s = 128; s > 0; s >>= 1) {
        if (tid < s) sred[tid] += sred[tid + s];
        __syncthreads();
    }
    if (tid == 0) ctx[b * C_ + c] = sred[0];
}

extern "C" void kernel_launch(void* const* d_in, const int* in_sizes, int n_in,
                              void* d_out, int out_size, void* d_ws, size_t ws_size,
                              hipStream_t stream) {
    const float* x      = (const float*)d_in[0];
    const float* st     = (const float*)d_in[1];
    const float* alpha  = (const float*)d_in[2];
    const float* convQw = (const float*)d_in[3];
    const float* convQb = (const float*)d_in[4];
    const float* Waw    = (const float*)d_in[5];
    const float* Wab    = (const float*)d_in[6];
    const float* Uaw    = (const float*)d_in[7];
    const float* Uab    = (const float*)d_in[8];
    const float* Ufw    = (const float*)d_in[9];
    const float* Ufb    = (const float*)d_in[10];
    const float* Vaw    = (const float*)d_in[11];
    const float* Vab    = (const float*)d_in[12];

    float* ws   = (float*)d_ws;
    float* beta = ws + WS_BETA;
    float* uat  = ws + WS_UAT;
    float* w2t  = ws + WS_W2T;
    float* bias = ws + WS_BIAS;
    float* e    = ws + WS_E;

    float* ctx  = (float*)d_out;             // [16, 684]
    float* aout = (float*)d_out + BS * C_;   // [16, 4096]

    k_beta<<<256, 256, 0, stream>>>(alpha, beta);
    k_uat<<<(C_ * NP + 255) / 256, 256, 0, stream>>>(Uaw, uat);
    k_w2t<<<(121 * NP + 255) / 256, 256, 0, stream>>>(Ufw, convQw, w2t);
    k_bias<<<BS * NP / 256, 256, 0, stream>>>(st, Waw, Wab, Ufw, Ufb, convQb, Uab, bias);
    k_score<<<dim3(HW / 16, BS), 256, 0, stream>>>(x, beta, uat, w2t, bias, Vaw, Vab, e);
    k_softmax<<<BS, 256, 0, stream>>>(e, aout);
    k_context<<<dim3(C_, BS), 256, 0, stream>>>(x, aout, ctx);
}

// Round 2
// 472.032 us; speedup vs baseline: 2.5047x; 2.5047x over previous
//
#include <hip/hip_runtime.h>
#include <math.h>

// dims
#define BS 16
#define C_ 684
#define Hh 32
#define Ww 128
#define HW 4096
#define Qc 256
#define Kk 11
#define NP 512
#define Nn 256
#define KTOT 832          // 684 + 121 padded to 26*32
#define NKT 26            // K-tiles of 32

// workspace layout (float offsets)
#define WS_BETA 0            // 16*4096 = 65536 floats
#define WS_BIAS 65536        // 16*512  = 8192
#define WS_E    73728        // 16*4096 = 65536
#define WS_ASW  139264       // A swizzled: 26*4*512*8 shorts = 425984 shorts (851968 B)
// total ~1.4 MB

typedef __attribute__((ext_vector_type(8))) short bf16x8;
typedef __attribute__((ext_vector_type(4))) float f32x4;

static __device__ __forceinline__ short f2bf(float f) {
    unsigned u = __builtin_bit_cast(unsigned, f);
    u += 0x7fff + ((u >> 16) & 1);          // RNE
    return (short)(u >> 16);
}

// ---- beta = sum_t alpha ------------------------------------------------
__global__ void k_beta(const float* __restrict__ alpha, float* __restrict__ beta) {
    int idx = blockIdx.x * 256 + threadIdx.x;            // 65536
    int b = idx >> 12, n = idx & 4095;
    const float* a = alpha + (size_t)b * 4 * HW + n;
    beta[idx] = a[0] + a[HW] + a[2 * HW] + a[3 * HW];
}

// ---- A swizzled: a_sw[kt][g][m][j] = A[k=kt*32+g*8+j][m] in bf16 -------
// A[k][m] = convUa_w[m][k] for k<684 ; (Uf_w @ convQ_w)[m][k-684] for k<805 ; 0 pad
__global__ void k_prep_a(const float* __restrict__ ua, const float* __restrict__ ufw,
                         const float* __restrict__ qw, short* __restrict__ a_sw) {
    int idx = blockIdx.x * 256 + threadIdx.x;            // 425984
    if (idx >= NKT * 4 * NP * 8) return;
    int j = idx & 7, m = (idx >> 3) & 511, g = (idx >> 12) & 3, kt = idx >> 14;
    int k = kt * 32 + g * 8 + j;
    float v = 0.f;
    if (k < C_) {
        v = ua[m * C_ + k];
    } else if (k < C_ + 121) {
        int tap = k - C_;
        const float* ur = ufw + m * Qc;
        float s = 0.f;
        for (int q = 0; q < Qc; ++q) s += ur[q] * qw[q * 121 + tap];
        v = s;
    }
    a_sw[idx] = f2bf(v);
}

// ---- Bias[b][p] = query + Wa_b + Uf_b + Uf_w@convQ_b + convUa_b --------
__global__ void k_bias(const float* __restrict__ st, const float* __restrict__ waw,
                       const float* __restrict__ wab, const float* __restrict__ ufw,
                       const float* __restrict__ ufb, const float* __restrict__ qb,
                       const float* __restrict__ uab, float* __restrict__ bias) {
    int idx = blockIdx.x * 256 + threadIdx.x;            // 8192
    int b = idx >> 9, p = idx & 511;
    float s = wab[p] + ufb[p] + uab[p];
    const float* sv = st + b * Nn;
    const float* wr = waw + p * Nn;
    for (int n = 0; n < Nn; ++n) s += sv[n] * wr[n];
    const float* ur = ufw + p * Qc;
    for (int q = 0; q < Qc; ++q) s += ur[q] * qb[q];
    bias[idx] = s;
}

// ---- fused MFMA GEMM + tanh/Va epilogue -> e[b][hw] --------------------
// block tile M=512 (all p) x N=32 pixels, K=832. 4 waves, wave = 128 rows.
__launch_bounds__(256, 3)
__global__ void k_gemm(const short* __restrict__ a_sw, const float* __restrict__ x,
                       const float* __restrict__ beta, const float* __restrict__ bias,
                       const float* __restrict__ vaw, const float* __restrict__ vab,
                       float* __restrict__ e) {
    __shared__ short As[4 * NP * 8];     // 32 KB : [g][m][j]
    __shared__ short Bs[4 * 32 * 8];     // 2 KB  : [g][n][j]
    __shared__ float ered[4][32];

    const int tid = threadIdx.x;
    const int lane = tid & 63, wid = tid >> 6;
    const int b = blockIdx.y, n0 = blockIdx.x * 32;
    const int q = lane >> 4, r = lane & 15;

    // B-staging role for this thread: 4 bf16 elems at (g=bg, n=bn, j=bh*4..+3)
    const int bn = tid & 31;
    const int bg = (tid >> 5) & 3;
    const int bh = tid >> 7;
    const int n_glob = n0 + bn;
    const int pr = n_glob >> 7, pc = n_glob & 127;
    const float* xb = x + (size_t)b * C_ * HW + n_glob;
    const float* betab = beta + b * HW;

    f32x4 acc[8][2] = {};

    for (int kt = 0; kt < NKT; ++kt) {
        __syncthreads();   // prior reads done before overwrite
        // ---- stage A: flat copy of 32 KB via global_load_lds width=16 ----
        const short* ag = a_sw + kt * (4 * NP * 8);
        #pragma unroll
        for (int i = 0; i < 8; ++i) {
            int chunk = i * 256 + wid * 64;   // wave-uniform base chunk
            __builtin_amdgcn_global_load_lds(
                (const __attribute__((address_space(1))) unsigned*)(ag + (size_t)(chunk + lane) * 8),
                (__attribute__((address_space(3))) unsigned*)&As[chunk * 8],
                16, 0, 0);
        }
        // ---- stage B: convert x / gather beta-im2col, swizzled ----
        {
            int kbase = kt * 32 + bg * 8 + bh * 4;
            unsigned pk[2];
            #pragma unroll
            for (int half = 0; half < 2; ++half) {
                unsigned w = 0;
                #pragma unroll
                for (int t = 0; t < 2; ++t) {
                    int k = kbase + half * 2 + t;
                    float f = 0.f;
                    if (k < C_) {
                        f = xb[(size_t)k * HW];
                    } else if (k < C_ + 121) {
                        int tap = k - C_;
                        int di = tap / 11, dj = tap - di * 11;
                        int rr = pr + di - 5, cc = pc + dj - 5;
                        if (rr >= 0 && rr < Hh && cc >= 0 && cc < Ww)
                            f = betab[rr * 128 + cc];
                    }
                    w |= ((unsigned)(unsigned short)f2bf(f)) << (16 * t);
                }
                pk[half] = w;
            }
            unsigned* dst = (unsigned*)&Bs[(bg * 32 + bn) * 8 + bh * 4];
            dst[0] = pk[0]; dst[1] = pk[1];
        }
        __syncthreads();   // staging visible (drains vmcnt for global_load_lds)

        // ---- fragments + MFMA ----
        bf16x8 af[8], bf[2];
        #pragma unroll
        for (int ms = 0; ms < 8; ++ms)
            af[ms] = *(const bf16x8*)&As[(q * NP + wid * 128 + ms * 16 + r) * 8];
        bf[0] = *(const bf16x8*)&Bs[(q * 32 + r) * 8];
        bf[1] = *(const bf16x8*)&Bs[(q * 32 + 16 + r) * 8];
        #pragma unroll
        for (int ms = 0; ms < 8; ++ms) {
            acc[ms][0] = __builtin_amdgcn_mfma_f32_16x16x32_bf16(af[ms], bf[0], acc[ms][0], 0, 0, 0);
            acc[ms][1] = __builtin_amdgcn_mfma_f32_16x16x32_bf16(af[ms], bf[1], acc[ms][1], 0, 0, 0);
        }
    }

    // ---- epilogue: e_partial = sum_rows Va[row] * tanh(acc + bias[row]) ----
    // C/D layout: col = lane&15, row = (lane>>4)*4 + reg
    float es0 = 0.f, es1 = 0.f;
    #pragma unroll
    for (int ms = 0; ms < 8; ++ms) {
        #pragma unroll
        for (int reg = 0; reg < 4; ++reg) {
            int row = wid * 128 + ms * 16 + q * 4 + reg;
            float bv = bias[b * NP + row];
            float vv = vaw[row];
            es0 += vv * tanhf(acc[ms][0][reg] + bv);
            es1 += vv * tanhf(acc[ms][1][reg] + bv);
        }
    }
    es0 += __shfl_xor(es0, 16, 64); es0 += __shfl_xor(es0, 32, 64);
    es1 += __shfl_xor(es1, 16, 64); es1 += __shfl_xor(es1, 32, 64);
    __syncthreads();
    if (lane < 16) { ered[wid][r] = es0; ered[wid][16 + r] = es1; }
    __syncthreads();
    if (tid < 32) {
        float s = ered[0][tid] + ered[1][tid] + ered[2][tid] + ered[3][tid] + vab[0];
        e[b * HW + n0 + tid] = s;
    }
}

// ---- softmax (reference form: exp / (sum + 1e-8)) ----------------------
__global__ void k_softmax(const float* __restrict__ e, float* __restrict__ aout) {
    __shared__ float sred[256];
    int b = blockIdx.x, tid = threadIdx.x;
    float vloc[16];
    float ps = 0.f;
#pragma unroll
    for (int k = 0; k < 16; ++k) {
        vloc[k] = expf(e[b * HW + tid + k * 256]);
        ps += vloc[k];
    }
    sred[tid] = ps;
    __syncthreads();
    for (int s = 128; s > 0; s >>= 1) {
        if (tid < s) sred[tid] += sred[tid + s];
        __syncthreads();
    }
    float scale = 1.f / (sred[0] + 1e-8f);
#pragma unroll
    for (int k = 0; k < 16; ++k) aout[b * HW + tid + k * 256] = vloc[k] * scale;
}

// ---- context[b][c] = sum_n alpha_t[b][n] * x[b][c][n] ------------------
__global__ void k_context(const float* __restrict__ x, const float* __restrict__ aout,
                          float* __restrict__ ctx) {
    __shared__ float sred[256];
    int c = blockIdx.x, b = blockIdx.y, tid = threadIdx.x;
    const float4* xr = (const float4*)(x + ((size_t)b * C_ + c) * HW);
    const float4* ar = (const float4*)(aout + b * HW);
    float acc = 0.f;
    for (int k = tid; k < 1024; k += 256) {
        float4 xv = xr[k], av = ar[k];
        acc += xv.x * av.x + xv.y * av.y + xv.z * av.z + xv.w * av.w;
    }
    sred[tid] = acc;
    __syncthreads();
    for (int s = 128; s > 0; s >>= 1) {
        if (tid < s) sred[tid] += sred[tid + s];
        __syncthreads();
    }
    if (tid == 0) ctx[b * C_ + c] = sred[0];
}

extern "C" void kernel_launch(void* const* d_in, const int* in_sizes, int n_in,
                              void* d_out, int out_size, void* d_ws, size_t ws_size,
                              hipStream_t stream) {
    const float* x      = (const float*)d_in[0];
    const float* st     = (const float*)d_in[1];
    const float* alpha  = (const float*)d_in[2];
    const float* convQw = (const float*)d_in[3];
    const float* convQb = (const float*)d_in[4];
    const float* Waw    = (const float*)d_in[5];
    const float* Wab    = (const float*)d_in[6];
    const float* Uaw    = (const float*)d_in[7];
    const float* Uab    = (const float*)d_in[8];
    const float* Ufw    = (const float*)d_in[9];
    const float* Ufb    = (const float*)d_in[10];
    const float* Vaw    = (const float*)d_in[11];
    const float* Vab    = (const float*)d_in[12];

    float* ws   = (float*)d_ws;
    float* beta = ws + WS_BETA;
    float* bias = ws + WS_BIAS;
    float* e    = ws + WS_E;
    short* a_sw = (short*)(ws + WS_ASW);

    float* ctx  = (float*)d_out;             // [16, 684]
    float* aout = (float*)d_out + BS * C_;   // [16, 4096]

    k_beta<<<256, 256, 0, stream>>>(alpha, beta);
    k_prep_a<<<(NKT * 4 * NP * 8 + 255) / 256, 256, 0, stream>>>(Uaw, Ufw, convQw, a_sw);
    k_bias<<<BS * NP / 256, 256, 0, stream>>>(st, Waw, Wab, Ufw, Ufb, convQb, Uab, bias);
    k_gemm<<<dim3(HW / 32, BS), 256, 0, stream>>>(a_sw, x, beta, bias, Vaw, Vab, e);
    k_softmax<<<BS, 256, 0, stream>>>(e, aout);
    k_context<<<dim3(C_, BS), 256, 0, stream>>>(x, aout, ctx);
}

// Round 3
// 429.686 us; speedup vs baseline: 2.7516x; 1.0985x over previous
//
#include <hip/hip_runtime.h>
#include <math.h>

// dims
#define BS 16
#define C_ 684
#define Hh 32
#define Ww 128
#define HW 4096
#define Qc 256
#define NP 512
#define Nn 256
#define NKT 26            // K-tiles of 32 (832 total: 684 x-ch + 121 taps + pad)
#define NB 64             // pixels per gemm block

// workspace layout (float offsets)
#define WS_BETA 0            // 16*4096 = 65536
#define WS_BIAS 65536        // 16*512  = 8192
#define WS_EEXP 73728        // 16*4096 = 65536
#define WS_INV  139264       // 16
#define WS_ASW  139280       // 26*4*512*8 shorts = 425984 shorts = 212992 floats

typedef __attribute__((ext_vector_type(8))) short bf16x8;
typedef __attribute__((ext_vector_type(4))) float f32x4;

static __device__ __forceinline__ short f2bf(float f) {
    unsigned u = __builtin_bit_cast(unsigned, f);
    u += 0x7fff + ((u >> 16) & 1);          // RNE
    return (short)(u >> 16);
}

static __device__ __forceinline__ float fast_tanh(float v) {
    float ax = fabsf(v);
    float t = __expf(-2.f * ax);            // in (0,1], no overflow
    float th = (1.f - t) * __builtin_amdgcn_rcpf(1.f + t);
    return copysignf(th, v);
}

// ---- fused prep: beta, A-swizzle, bias ---------------------------------
// grid = 256 (beta) + 1664 (a_sw) + 32 (bias) = 1952 blocks
__global__ void k_prep(const float* __restrict__ alpha, const float* __restrict__ ua,
                       const float* __restrict__ ufw, const float* __restrict__ qw,
                       const float* __restrict__ st, const float* __restrict__ waw,
                       const float* __restrict__ wab, const float* __restrict__ ufb,
                       const float* __restrict__ qb, const float* __restrict__ uab,
                       float* __restrict__ beta, short* __restrict__ a_sw,
                       float* __restrict__ bias) {
    int part = blockIdx.x, tid = threadIdx.x;
    if (part < 256) {
        // beta = sum_t alpha
        int idx = part * 256 + tid;
        int b = idx >> 12, n = idx & 4095;
        const float* a = alpha + (size_t)b * 4 * HW + n;
        beta[idx] = a[0] + a[HW] + a[2 * HW] + a[3 * HW];
    } else if (part < 1920) {
        // a_sw[kt][g][m][j] = A[k][m] bf16, k = kt*32+g*8+j
        int idx = (part - 256) * 256 + tid;          // < 425984
        int j = idx & 7, m = (idx >> 3) & 511, g = (idx >> 12) & 3, kt = idx >> 14;
        int k = kt * 32 + g * 8 + j;
        float v = 0.f;
        if (k < C_) {
            v = ua[m * C_ + k];
        } else if (k < C_ + 121) {
            int tap = k - C_;
            const float* ur = ufw + m * Qc;
            float s = 0.f;
            for (int q = 0; q < Qc; ++q) s += ur[q] * qw[q * 121 + tap];
            v = s;
        }
        a_sw[idx] = f2bf(v);
    } else {
        // bias[b][p]
        int idx = (part - 1920) * 256 + tid;         // < 8192
        int b = idx >> 9, p = idx & 511;
        float s = wab[p] + ufb[p] + uab[p];
        const float* sv = st + b * Nn;
        const float* wr = waw + p * Nn;
        for (int n = 0; n < Nn; ++n) s += sv[n] * wr[n];
        const float* ur = ufw + p * Qc;
        for (int q = 0; q < Qc; ++q) s += ur[q] * qb[q];
        bias[idx] = s;
    }
}

// ---- fused MFMA GEMM + tanh/Va/exp epilogue -> eexp[b][hw] -------------
// block: M=512 x N=64, K=832. A-frags direct from L2 (no LDS), B via LDS.
__launch_bounds__(256, 2)
__global__ void k_gemm(const short* __restrict__ a_sw, const float* __restrict__ x,
                       const float* __restrict__ beta, const float* __restrict__ bias,
                       const float* __restrict__ vaw, const float* __restrict__ vab,
                       float* __restrict__ eexp) {
    __shared__ short Bs[4 * NB * 8];     // 4 KB : [g][n][j]
    __shared__ float ered[4][NB];

    const int tid = threadIdx.x;
    const int lane = tid & 63, wid = tid >> 6;
    const int b = blockIdx.y, n0 = blockIdx.x * NB;
    const int q = lane >> 4, r = lane & 15;

    // B-staging role: pixel sn, k-group sg, 8 j's -> one b128 LDS write
    const int sn = tid & 63;
    const int sg = tid >> 6;
    const int n_glob = n0 + sn;
    const int pr = n_glob >> 7, pc = n_glob & 127;
    const float* xb = x + (size_t)b * C_ * HW + n_glob;
    const float* betab = beta + b * HW;

    f32x4 acc[8][4] = {};

    for (int kt = 0; kt < NKT; ++kt) {
        // ---- A fragments: direct global (L2-resident), coalesced b128 ----
        const short* ag = a_sw + kt * (4 * NP * 8);
        bf16x8 af[8];
        #pragma unroll
        for (int ms = 0; ms < 8; ++ms)
            af[ms] = *(const bf16x8*)(ag + (size_t)(q * NP + wid * 128 + ms * 16 + r) * 8);

        // ---- B values: x convert / beta im2col, packed 8 bf16 ----
        unsigned pk[4];
        {
            int kbase = kt * 32 + sg * 8;
            #pragma unroll
            for (int half = 0; half < 4; ++half) {
                unsigned w = 0;
                #pragma unroll
                for (int t = 0; t < 2; ++t) {
                    int k = kbase + half * 2 + t;
                    float f = 0.f;
                    if (k < C_) {
                        f = xb[(size_t)k * HW];
                    } else if (k < C_ + 121) {
                        int tap = k - C_;
                        int di = tap / 11, dj = tap - di * 11;
                        int rr = pr + di - 5, cc = pc + dj - 5;
                        if (rr >= 0 && rr < Hh && cc >= 0 && cc < Ww)
                            f = betab[rr * 128 + cc];
                    }
                    w |= ((unsigned)(unsigned short)f2bf(f)) << (16 * t);
                }
                pk[half] = w;
            }
        }
        __syncthreads();   // prior Bs reads done
        *(uint4*)&Bs[(sg * NB + sn) * 8] = make_uint4(pk[0], pk[1], pk[2], pk[3]);
        __syncthreads();   // Bs visible

        bf16x8 bf[4];
        #pragma unroll
        for (int ns = 0; ns < 4; ++ns)
            bf[ns] = *(const bf16x8*)&Bs[(q * NB + ns * 16 + r) * 8];
        #pragma unroll
        for (int ms = 0; ms < 8; ++ms)
            #pragma unroll
            for (int ns = 0; ns < 4; ++ns)
                acc[ms][ns] = __builtin_amdgcn_mfma_f32_16x16x32_bf16(af[ms], bf[ns], acc[ms][ns], 0, 0, 0);
    }

    // ---- epilogue: e = sum_rows Va[row] * tanh(acc + bias[row]); exp ----
    // C/D layout: col = lane&15, row = (lane>>4)*4 + reg
    float es[4] = {0.f, 0.f, 0.f, 0.f};
    #pragma unroll
    for (int ms = 0; ms < 8; ++ms) {
        #pragma unroll
        for (int reg = 0; reg < 4; ++reg) {
            int row = wid * 128 + ms * 16 + q * 4 + reg;
            float bv = bias[b * NP + row];
            float vv = vaw[row];
            #pragma unroll
            for (int ns = 0; ns < 4; ++ns)
                es[ns] += vv * fast_tanh(acc[ms][ns][reg] + bv);
        }
    }
    #pragma unroll
    for (int ns = 0; ns < 4; ++ns) {
        es[ns] += __shfl_xor(es[ns], 16, 64);
        es[ns] += __shfl_xor(es[ns], 32, 64);
    }
    if (lane < 16) {
        #pragma unroll
        for (int ns = 0; ns < 4; ++ns) ered[wid][ns * 16 + r] = es[ns];
    }
    __syncthreads();
    if (tid < NB) {
        float s = ered[0][tid] + ered[1][tid] + ered[2][tid] + ered[3][tid] + vab[0];
        eexp[b * HW + n0 + tid] = expf(s);
    }
}

// ---- per-batch sum of eexp -> inv = 1/(S + 1e-8) -----------------------
__global__ void k_sum(const float* __restrict__ eexp, float* __restrict__ inv) {
    __shared__ float sred[256];
    int b = blockIdx.x, tid = threadIdx.x;
    const float4* er = (const float4*)(eexp + b * HW);
    float ps = 0.f;
    for (int k = tid; k < 1024; k += 256) {
        float4 v = er[k];
        ps += v.x + v.y + v.z + v.w;
    }
    sred[tid] = ps;
    __syncthreads();
    for (int s = 128; s > 0; s >>= 1) {
        if (tid < s) sred[tid] += sred[tid + s];
        __syncthreads();
    }
    if (tid == 0) inv[b] = 1.f / (sred[0] + 1e-8f);
}

// ---- finish: context (c < C_) and alpha writeback (c == C_) ------------
__global__ void k_finish(const float* __restrict__ x, const float* __restrict__ eexp,
                         const float* __restrict__ inv, float* __restrict__ ctx,
                         float* __restrict__ aout) {
    __shared__ float sred[256];
    int c = blockIdx.x, b = blockIdx.y, tid = threadIdx.x;
    float iv = inv[b];
    if (c == C_) {
        for (int k = tid; k < HW; k += 256) aout[b * HW + k] = eexp[b * HW + k] * iv;
        return;
    }
    const float4* xr = (const float4*)(x + ((size_t)b * C_ + c) * HW);
    const float4* er = (const float4*)(eexp + b * HW);
    float acc = 0.f;
    for (int k = tid; k < 1024; k += 256) {
        float4 xv = xr[k], ev = er[k];
        acc += xv.x * ev.x + xv.y * ev.y + xv.z * ev.z + xv.w * ev.w;
    }
    sred[tid] = acc;
    __syncthreads();
    for (int s = 128; s > 0; s >>= 1) {
        if (tid < s) sred[tid] += sred[tid + s];
        __syncthreads();
    }
    if (tid == 0) ctx[b * C_ + c] = sred[0] * iv;
}

extern "C" void kernel_launch(void* const* d_in, const int* in_sizes, int n_in,
                              void* d_out, int out_size, void* d_ws, size_t ws_size,
                              hipStream_t stream) {
    const float* x      = (const float*)d_in[0];
    const float* st     = (const float*)d_in[1];
    const float* alpha  = (const float*)d_in[2];
    const float* convQw = (const float*)d_in[3];
    const float* convQb = (const float*)d_in[4];
    const float* Waw    = (const float*)d_in[5];
    const float* Wab    = (const float*)d_in[6];
    const float* Uaw    = (const float*)d_in[7];
    const float* Uab    = (const float*)d_in[8];
    const float* Ufw    = (const float*)d_in[9];
    const float* Ufb    = (const float*)d_in[10];
    const float* Vaw    = (const float*)d_in[11];
    const float* Vab    = (const float*)d_in[12];

    float* ws   = (float*)d_ws;
    float* beta = ws + WS_BETA;
    float* bias = ws + WS_BIAS;
    float* eexp = ws + WS_EEXP;
    float* inv  = ws + WS_INV;
    short* a_sw = (short*)(ws + WS_ASW);

    float* ctx  = (float*)d_out;             // [16, 684]
    float* aout = (float*)d_out + BS * C_;   // [16, 4096]

    k_prep<<<1952, 256, 0, stream>>>(alpha, Uaw, Ufw, convQw, st, Waw, Wab, Ufb,
                                     convQb, Uab, beta, a_sw, bias);
    k_gemm<<<dim3(HW / NB, BS), 256, 0, stream>>>(a_sw, x, beta, bias, Vaw, Vab, eexp);
    k_sum<<<BS, 256, 0, stream>>>(eexp, inv);
    k_finish<<<dim3(C_ + 1, BS), 256, 0, stream>>>(x, eexp, inv, ctx, aout);
}

// Round 4
// 369.474 us; speedup vs baseline: 3.2000x; 1.1630x over previous
//
#include <hip/hip_runtime.h>
#include <math.h>

// dims
#define BS 16
#define C_ 684
#define Hh 32
#define Ww 128
#define HW 4096
#define Qc 256
#define NP 512
#define Nn 256
#define NKT 26            // K-tiles of 32 (832 total: 684 x-ch + 121 taps + pad)
#define NB 64             // pixels per gemm block

// workspace layout (float offsets)
#define WS_BETA 0            // 16*4096 = 65536
#define WS_BIAS 65536        // 16*512  = 8192
#define WS_EEXP 73728        // 16*4096 = 65536
#define WS_ESUM 139264       // 16
#define WS_ASW  139280       // 26*4*512*8 shorts = 425984 shorts = 212992 floats

typedef __attribute__((ext_vector_type(8))) short bf16x8;
typedef __attribute__((ext_vector_type(4))) float f32x4;

static __device__ __forceinline__ short f2bf(float f) {
    unsigned u = __builtin_bit_cast(unsigned, f);
    u += 0x7fff + ((u >> 16) & 1);          // RNE
    return (short)(u >> 16);
}

static __device__ __forceinline__ float fast_tanh(float v) {
    float ax = fabsf(v);
    float t = __expf(-2.f * ax);            // in (0,1], no overflow
    float th = (1.f - t) * __builtin_amdgcn_rcpf(1.f + t);
    return copysignf(th, v);
}

// ---- fused prep: beta, A-swizzle, bias, esum-zero ----------------------
// grid = 256 (beta) + 1664 (a_sw) + 32 (bias) + 1 (esum) = 1953 blocks
__global__ void k_prep(const float* __restrict__ alpha, const float* __restrict__ ua,
                       const float* __restrict__ ufw, const float* __restrict__ qw,
                       const float* __restrict__ st, const float* __restrict__ waw,
                       const float* __restrict__ wab, const float* __restrict__ ufb,
                       const float* __restrict__ qb, const float* __restrict__ uab,
                       float* __restrict__ beta, short* __restrict__ a_sw,
                       float* __restrict__ bias, float* __restrict__ esum) {
    int part = blockIdx.x, tid = threadIdx.x;
    if (part < 256) {
        // beta = sum_t alpha
        int idx = part * 256 + tid;
        int b = idx >> 12, n = idx & 4095;
        const float* a = alpha + (size_t)b * 4 * HW + n;
        beta[idx] = a[0] + a[HW] + a[2 * HW] + a[3 * HW];
    } else if (part < 1920) {
        // a_sw[kt][g][m][j] = A[k][m] bf16, k = kt*32+g*8+j
        int idx = (part - 256) * 256 + tid;          // < 425984
        int j = idx & 7, m = (idx >> 3) & 511, g = (idx >> 12) & 3, kt = idx >> 14;
        int k = kt * 32 + g * 8 + j;
        float v = 0.f;
        if (k < C_) {
            v = ua[m * C_ + k];
        } else if (k < C_ + 121) {
            int tap = k - C_;
            const float* ur = ufw + m * Qc;
            float s = 0.f;
            for (int q = 0; q < Qc; ++q) s += ur[q] * qw[q * 121 + tap];
            v = s;
        }
        a_sw[idx] = f2bf(v);
    } else if (part < 1952) {
        // bias[b][p]
        int idx = (part - 1920) * 256 + tid;         // < 8192
        int b = idx >> 9, p = idx & 511;
        float s = wab[p] + ufb[p] + uab[p];
        const float* sv = st + b * Nn;
        const float* wr = waw + p * Nn;
        for (int n = 0; n < Nn; ++n) s += sv[n] * wr[n];
        const float* ur = ufw + p * Qc;
        for (int q = 0; q < Qc; ++q) s += ur[q] * qb[q];
        bias[idx] = s;
    } else {
        if (tid < BS) esum[tid] = 0.f;
    }
}

// ---- fused MFMA GEMM + tanh/Va/exp epilogue -> eexp, esum --------------
// block: M=512 x N=64, K=832. A-frags direct from L2; B staged via LDS
// with distance-2 register prefetch of the fp32 source values.
__launch_bounds__(256, 2)
__global__ void k_gemm(const short* __restrict__ a_sw, const float* __restrict__ x,
                       const float* __restrict__ beta, const float* __restrict__ bias,
                       const float* __restrict__ vaw, const float* __restrict__ vab,
                       float* __restrict__ eexp, float* __restrict__ esum) {
    __shared__ short Bs[4 * NB * 8];     // 4 KB : [g][n][j]
    __shared__ float ered[4][NB];

    const int tid = threadIdx.x;
    const int lane = tid & 63, wid = tid >> 6;
    const int b = blockIdx.y, n0 = blockIdx.x * NB;
    const int q = lane >> 4, r = lane & 15;

    // staging role: pixel sn, k-group sg (wave-uniform), 8 j's
    const int sn = tid & 63;
    const int sg = tid >> 6;
    const int n_glob = n0 + sn;
    const int pr = n_glob >> 7, pc = n_glob & 127;
    const float* xb = x + (size_t)b * C_ * HW + n_glob;
    const float* betab = beta + b * HW;

    f32x4 acc[8][4] = {};
    float fv[2][8];

    // distance-2 prefetch of staging source values
    #define LDSTAGE(KT, DST)                                                  \
    {                                                                         \
        int kbase = (KT) * 32 + sg * 8;                                       \
        _Pragma("unroll")                                                     \
        for (int j = 0; j < 8; ++j) {                                         \
            int k = kbase + j;                                                \
            float f = 0.f;                                                    \
            if (k < C_) {                                                     \
                f = xb[(size_t)k * HW];                                       \
            } else if (k < C_ + 121) {                                        \
                int tap = k - C_;                                             \
                int di = tap / 11, dj = tap - di * 11;                        \
                int rr = pr + di - 5, cc = pc + dj - 5;                       \
                if (rr >= 0 && rr < Hh && cc >= 0 && cc < Ww)                 \
                    f = betab[rr * 128 + cc];                                 \
            }                                                                 \
            (DST)[j] = f;                                                     \
        }                                                                     \
    }

    LDSTAGE(0, fv[0]);
    LDSTAGE(1, fv[1]);

    const short* ap = a_sw + (size_t)(q * NP + wid * 128 + r) * 8;

    #pragma unroll 2
    for (int kt = 0; kt < NKT; ++kt) {
        __syncthreads();   // prior Bs reads done
        {
            const float* f = fv[kt & 1];
            unsigned pk[4];
            #pragma unroll
            for (int h = 0; h < 4; ++h)
                pk[h] = (unsigned)(unsigned short)f2bf(f[2 * h]) |
                        ((unsigned)(unsigned short)f2bf(f[2 * h + 1]) << 16);
            *(uint4*)&Bs[(sg * NB + sn) * 8] = make_uint4(pk[0], pk[1], pk[2], pk[3]);
        }
        __syncthreads();   // Bs visible

        bf16x8 bf[4];
        #pragma unroll
        for (int ns = 0; ns < 4; ++ns)
            bf[ns] = *(const bf16x8*)&Bs[(q * NB + ns * 16 + r) * 8];

        // A fragments for this kt: coalesced b128 from L2
        bf16x8 af[8];
        const short* ak = ap + (size_t)kt * 4 * NP * 8;
        #pragma unroll
        for (int ms = 0; ms < 8; ++ms)
            af[ms] = *(const bf16x8*)(ak + ms * 16 * 8);

        // prefetch staging values for kt+2 (overlaps with MFMA below)
        if (kt < NKT - 2) LDSTAGE(kt + 2, fv[kt & 1]);

        #pragma unroll
        for (int ms = 0; ms < 8; ++ms)
            #pragma unroll
            for (int ns = 0; ns < 4; ++ns)
                acc[ms][ns] = __builtin_amdgcn_mfma_f32_16x16x32_bf16(af[ms], bf[ns], acc[ms][ns], 0, 0, 0);
    }
    #undef LDSTAGE

    // ---- epilogue: e = sum_rows Va[row]*tanh(acc+bias[row]); exp; esum ----
    // C/D layout: col = lane&15, row = (lane>>4)*4 + reg
    float es[4] = {0.f, 0.f, 0.f, 0.f};
    #pragma unroll
    for (int ms = 0; ms < 8; ++ms) {
        #pragma unroll
        for (int reg = 0; reg < 4; ++reg) {
            int row = wid * 128 + ms * 16 + q * 4 + reg;
            float bv = bias[b * NP + row];
            float vv = vaw[row];
            #pragma unroll
            for (int ns = 0; ns < 4; ++ns)
                es[ns] += vv * fast_tanh(acc[ms][ns][reg] + bv);
        }
    }
    #pragma unroll
    for (int ns = 0; ns < 4; ++ns) {
        es[ns] += __shfl_xor(es[ns], 16, 64);
        es[ns] += __shfl_xor(es[ns], 32, 64);
    }
    if (lane < 16) {
        #pragma unroll
        for (int ns = 0; ns < 4; ++ns) ered[wid][ns * 16 + r] = es[ns];
    }
    __syncthreads();
    if (tid < NB) {          // exactly wave 0
        float s = ered[0][tid] + ered[1][tid] + ered[2][tid] + ered[3][tid] + vab[0];
        float ex = expf(s);
        eexp[b * HW + n0 + tid] = ex;
        float ps = ex;
        #pragma unroll
        for (int off = 32; off > 0; off >>= 1) ps += __shfl_xor(ps, off, 64);
        if (tid == 0) atomicAdd(&esum[b], ps);
    }
}

// ---- finish: context rows (wave-per-row) + alpha writeback -------------
// grid = dim3(172, 16): part<171 -> 4 c-rows per block; part==171 -> aout
__global__ void k_finish(const float* __restrict__ x, const float* __restrict__ eexp,
                         const float* __restrict__ esum, float* __restrict__ ctx,
                         float* __restrict__ aout) {
    int part = blockIdx.x, b = blockIdx.y, tid = threadIdx.x;
    float iv = 1.f / (esum[b] + 1e-8f);
    if (part == 171) {
        for (int k = tid; k < HW; k += 256) aout[b * HW + k] = eexp[b * HW + k] * iv;
        return;
    }
    int wid = tid >> 6, lane = tid & 63;
    int c = part * 4 + wid;                          // < 684
    const float4* xr = (const float4*)(x + ((size_t)b * C_ + c) * HW);
    const float4* er = (const float4*)(eexp + b * HW);
    float acc = 0.f;
    #pragma unroll 4
    for (int k = lane; k < 1024; k += 64) {
        float4 xv = xr[k], ev = er[k];
        acc += xv.x * ev.x + xv.y * ev.y + xv.z * ev.z + xv.w * ev.w;
    }
    #pragma unroll
    for (int off = 32; off > 0; off >>= 1) acc += __shfl_xor(acc, off, 64);
    if (lane == 0) ctx[b * C_ + c] = acc * iv;
}

extern "C" void kernel_launch(void* const* d_in, const int* in_sizes, int n_in,
                              void* d_out, int out_size, void* d_ws, size_t ws_size,
                              hipStream_t stream) {
    const float* x      = (const float*)d_in[0];
    const float* st     = (const float*)d_in[1];
    const float* alpha  = (const float*)d_in[2];
    const float* convQw = (const float*)d_in[3];
    const float* convQb = (const float*)d_in[4];
    const float* Waw    = (const float*)d_in[5];
    const float* Wab    = (const float*)d_in[6];
    const float* Uaw    = (const float*)d_in[7];
    const float* Uab    = (const float*)d_in[8];
    const float* Ufw    = (const float*)d_in[9];
    const float* Ufb    = (const float*)d_in[10];
    const float* Vaw    = (const float*)d_in[11];
    const float* Vab    = (const float*)d_in[12];

    float* ws   = (float*)d_ws;
    float* beta = ws + WS_BETA;
    float* bias = ws + WS_BIAS;
    float* eexp = ws + WS_EEXP;
    float* esum = ws + WS_ESUM;
    short* a_sw = (short*)(ws + WS_ASW);

    float* ctx  = (float*)d_out;             // [16, 684]
    float* aout = (float*)d_out + BS * C_;   // [16, 4096]

    k_prep<<<1953, 256, 0, stream>>>(alpha, Uaw, Ufw, convQw, st, Waw, Wab, Ufb,
                                     convQb, Uab, beta, a_sw, bias, esum);
    k_gemm<<<dim3(HW / NB, BS), 256, 0, stream>>>(a_sw, x, beta, bias, Vaw, Vab, eexp, esum);
    k_finish<<<dim3(172, BS), 256, 0, stream>>>(x, eexp, esum, ctx, aout);
}

// Round 5
// 366.762 us; speedup vs baseline: 3.2237x; 1.0074x over previous
//
#include <hip/hip_runtime.h>
#include <math.h>

// dims
#define BS 16
#define C_ 684
#define Hh 32
#define Ww 128
#define HW 4096
#define Qc 256
#define NP 512
#define Nn 256
#define NKT 26            // K-tiles of 32 (832 total: 684 x-ch + 121 taps + pad)
#define NB 64             // pixels per gemm block

// workspace layout (float offsets)
#define WS_BETA 0            // 16*4096 = 65536
#define WS_BIAS 65536        // 16*512  = 8192
#define WS_EEXP 73728        // 16*4096 = 65536
#define WS_ESUM 139264       // 16
#define WS_ASW  139280       // 26*4*512*8 shorts = 425984 shorts = 212992 floats

typedef __attribute__((ext_vector_type(8))) short bf16x8;
typedef __attribute__((ext_vector_type(4))) float f32x4;

static __device__ __forceinline__ short f2bf(float f) {
    unsigned u = __builtin_bit_cast(unsigned, f);
    u += 0x7fff + ((u >> 16) & 1);          // RNE
    return (short)(u >> 16);
}

static __device__ __forceinline__ float fast_tanh(float v) {
    float ax = fabsf(v);
    float t = __expf(-2.f * ax);            // in (0,1], no overflow
    float th = (1.f - t) * __builtin_amdgcn_rcpf(1.f + t);
    return copysignf(th, v);
}

// ---- fused prep: beta, A-swizzle, bias, esum-zero ----------------------
__global__ void k_prep(const float* __restrict__ alpha, const float* __restrict__ ua,
                       const float* __restrict__ ufw, const float* __restrict__ qw,
                       const float* __restrict__ st, const float* __restrict__ waw,
                       const float* __restrict__ wab, const float* __restrict__ ufb,
                       const float* __restrict__ qb, const float* __restrict__ uab,
                       float* __restrict__ beta, short* __restrict__ a_sw,
                       float* __restrict__ bias, float* __restrict__ esum) {
    int part = blockIdx.x, tid = threadIdx.x;
    if (part < 256) {
        // beta = sum_t alpha
        int idx = part * 256 + tid;
        int b = idx >> 12, n = idx & 4095;
        const float* a = alpha + (size_t)b * 4 * HW + n;
        beta[idx] = a[0] + a[HW] + a[2 * HW] + a[3 * HW];
    } else if (part < 1920) {
        // a_sw[kt][g][m][j] = A[k][m] bf16, k = kt*32+g*8+j
        int idx = (part - 256) * 256 + tid;          // < 425984
        int j = idx & 7, m = (idx >> 3) & 511, g = (idx >> 12) & 3, kt = idx >> 14;
        int k = kt * 32 + g * 8 + j;
        float v = 0.f;
        if (k < C_) {
            v = ua[m * C_ + k];
        } else if (k < C_ + 121) {
            int tap = k - C_;
            const float* ur = ufw + m * Qc;
            float s = 0.f;
            for (int q = 0; q < Qc; ++q) s += ur[q] * qw[q * 121 + tap];
            v = s;
        }
        a_sw[idx] = f2bf(v);
    } else if (part < 1952) {
        // bias[b][p]
        int idx = (part - 1920) * 256 + tid;         // < 8192
        int b = idx >> 9, p = idx & 511;
        float s = wab[p] + ufb[p] + uab[p];
        const float* sv = st + b * Nn;
        const float* wr = waw + p * Nn;
        for (int n = 0; n < Nn; ++n) s += sv[n] * wr[n];
        const float* ur = ufw + p * Qc;
        for (int q = 0; q < Qc; ++q) s += ur[q] * qb[q];
        bias[idx] = s;
    } else {
        if (tid < BS) esum[tid] = 0.f;
    }
}

// ---- fused MFMA GEMM + tanh/Va/exp epilogue -> eexp, esum --------------
// block: M=512 x N=64, K=832. Per kt: A-frag loads hoisted to iteration
// top (L2 latency covered by pack+barrier+ds_read); Bs double-buffered so
// only ONE barrier per kt; B source values prefetched at distance 2.
__launch_bounds__(256, 2)
__global__ void k_gemm(const short* __restrict__ a_sw, const float* __restrict__ x,
                       const float* __restrict__ beta, const float* __restrict__ bias,
                       const float* __restrict__ vaw, const float* __restrict__ vab,
                       float* __restrict__ eexp, float* __restrict__ esum) {
    __shared__ short Bs[2][4 * NB * 8];  // 2 x 4 KB : [g][n][j]
    __shared__ float ered[4][NB];

    const int tid = threadIdx.x;
    const int lane = tid & 63, wid = tid >> 6;
    const int b = blockIdx.y, n0 = blockIdx.x * NB;
    const int q = lane >> 4, r = lane & 15;

    // staging role: pixel sn, k-group sg (wave-uniform), 8 j's
    const int sn = tid & 63;
    const int sg = tid >> 6;
    const int n_glob = n0 + sn;
    const int pr = n_glob >> 7, pc = n_glob & 127;
    const float* xb = x + (size_t)b * C_ * HW + n_glob;
    const float* betab = beta + b * HW;

    f32x4 acc[8][4] = {};
    float fv[2][8];

    #define LDSTAGE(KT, DST)                                                  \
    {                                                                         \
        int kbase = (KT) * 32 + sg * 8;                                       \
        _Pragma("unroll")                                                     \
        for (int j = 0; j < 8; ++j) {                                         \
            int k = kbase + j;                                                \
            float f = 0.f;                                                    \
            if (k < C_) {                                                     \
                f = xb[(size_t)k * HW];                                       \
            } else if (k < C_ + 121) {                                        \
                int tap = k - C_;                                             \
                int di = tap / 11, dj = tap - di * 11;                        \
                int rr = pr + di - 5, cc = pc + dj - 5;                       \
                if (rr >= 0 && rr < Hh && cc >= 0 && cc < Ww)                 \
                    f = betab[rr * 128 + cc];                                 \
            }                                                                 \
            (DST)[j] = f;                                                     \
        }                                                                     \
    }

    LDSTAGE(0, fv[0]);
    LDSTAGE(1, fv[1]);

    const short* ap = a_sw + (size_t)(q * NP + wid * 128 + r) * 8;

    #pragma unroll 2
    for (int kt = 0; kt < NKT; ++kt) {
        // ---- A fragments first: L2 latency covered by pack+barrier+ds_read
        bf16x8 af[8];
        const short* ak = ap + (size_t)kt * 4 * NP * 8;
        #pragma unroll
        for (int ms = 0; ms < 8; ++ms)
            af[ms] = *(const bf16x8*)(ak + ms * 16 * 8);

        // ---- pack B values (prefetched 2 iters ago) and store to LDS ----
        {
            const float* f = fv[kt & 1];
            unsigned pk[4];
            #pragma unroll
            for (int h = 0; h < 4; ++h)
                pk[h] = (unsigned)(unsigned short)f2bf(f[2 * h]) |
                        ((unsigned)(unsigned short)f2bf(f[2 * h + 1]) << 16);
            *(uint4*)&Bs[kt & 1][(sg * NB + sn) * 8] = make_uint4(pk[0], pk[1], pk[2], pk[3]);
        }
        __syncthreads();   // single barrier per kt (dbuf makes WAR safe)

        bf16x8 bf[4];
        #pragma unroll
        for (int ns = 0; ns < 4; ++ns)
            bf[ns] = *(const bf16x8*)&Bs[kt & 1][(q * NB + ns * 16 + r) * 8];

        // prefetch staging values for kt+2 (overlaps with MFMA below)
        if (kt < NKT - 2) LDSTAGE(kt + 2, fv[kt & 1]);

        #pragma unroll
        for (int ms = 0; ms < 8; ++ms)
            #pragma unroll
            for (int ns = 0; ns < 4; ++ns)
                acc[ms][ns] = __builtin_amdgcn_mfma_f32_16x16x32_bf16(af[ms], bf[ns], acc[ms][ns], 0, 0, 0);
    }
    #undef LDSTAGE

    // ---- epilogue: e = sum_rows Va[row]*tanh(acc+bias[row]); exp; esum ----
    // C/D layout: col = lane&15, row = (lane>>4)*4 + reg
    float es[4] = {0.f, 0.f, 0.f, 0.f};
    #pragma unroll
    for (int ms = 0; ms < 8; ++ms) {
        #pragma unroll
        for (int reg = 0; reg < 4; ++reg) {
            int row = wid * 128 + ms * 16 + q * 4 + reg;
            float bv = bias[b * NP + row];
            float vv = vaw[row];
            #pragma unroll
            for (int ns = 0; ns < 4; ++ns)
                es[ns] += vv * fast_tanh(acc[ms][ns][reg] + bv);
        }
    }
    #pragma unroll
    for (int ns = 0; ns < 4; ++ns) {
        es[ns] += __shfl_xor(es[ns], 16, 64);
        es[ns] += __shfl_xor(es[ns], 32, 64);
    }
    if (lane < 16) {
        #pragma unroll
        for (int ns = 0; ns < 4; ++ns) ered[wid][ns * 16 + r] = es[ns];
    }
    __syncthreads();
    if (tid < NB) {          // exactly wave 0
        float s = ered[0][tid] + ered[1][tid] + ered[2][tid] + ered[3][tid] + vab[0];
        float ex = expf(s);
        eexp[b * HW + n0 + tid] = ex;
        float ps = ex;
        #pragma unroll
        for (int off = 32; off > 0; off >>= 1) ps += __shfl_xor(ps, off, 64);
        if (tid == 0) atomicAdd(&esum[b], ps);
    }
}

// ---- finish: context rows (wave-per-row) + alpha writeback -------------
__global__ void k_finish(const float* __restrict__ x, const float* __restrict__ eexp,
                         const float* __restrict__ esum, float* __restrict__ ctx,
                         float* __restrict__ aout) {
    int part = blockIdx.x, b = blockIdx.y, tid = threadIdx.x;
    float iv = 1.f / (esum[b] + 1e-8f);
    if (part == 171) {
        for (int k = tid; k < HW; k += 256) aout[b * HW + k] = eexp[b * HW + k] * iv;
        return;
    }
    int wid = tid >> 6, lane = tid & 63;
    int c = part * 4 + wid;                          // < 684
    const float4* xr = (const float4*)(x + ((size_t)b * C_ + c) * HW);
    const float4* er = (const float4*)(eexp + b * HW);
    float acc = 0.f;
    #pragma unroll 8
    for (int k = lane; k < 1024; k += 64) {
        float4 xv = xr[k], ev = er[k];
        acc += xv.x * ev.x + xv.y * ev.y + xv.z * ev.z + xv.w * ev.w;
    }
    #pragma unroll
    for (int off = 32; off > 0; off >>= 1) acc += __shfl_xor(acc, off, 64);
    if (lane == 0) ctx[b * C_ + c] = acc * iv;
}

extern "C" void kernel_launch(void* const* d_in, const int* in_sizes, int n_in,
                              void* d_out, int out_size, void* d_ws, size_t ws_size,
                              hipStream_t stream) {
    const float* x      = (const float*)d_in[0];
    const float* st     = (const float*)d_in[1];
    const float* alpha  = (const float*)d_in[2];
    const float* convQw = (const float*)d_in[3];
    const float* convQb = (const float*)d_in[4];
    const float* Waw    = (const float*)d_in[5];
    const float* Wab    = (const float*)d_in[6];
    const float* Uaw    = (const float*)d_in[7];
    const float* Uab    = (const float*)d_in[8];
    const float* Ufw    = (const float*)d_in[9];
    const float* Ufb    = (const float*)d_in[10];
    const float* Vaw    = (const float*)d_in[11];
    const float* Vab    = (const float*)d_in[12];

    float* ws   = (float*)d_ws;
    float* beta = ws + WS_BETA;
    float* bias = ws + WS_BIAS;
    float* eexp = ws + WS_EEXP;
    float* esum = ws + WS_ESUM;
    short* a_sw = (short*)(ws + WS_ASW);

    float* ctx  = (float*)d_out;             // [16, 684]
    float* aout = (float*)d_out + BS * C_;   // [16, 4096]

    k_prep<<<1953, 256, 0, stream>>>(alpha, Uaw, Ufw, convQw, st, Waw, Wab, Ufb,
                                     convQb, Uab, beta, a_sw, bias, esum);
    k_gemm<<<dim3(HW / NB, BS), 256, 0, stream>>>(a_sw, x, beta, bias, Vaw, Vab, eexp, esum);
    k_finish<<<dim3(172, BS), 256, 0, stream>>>(x, eexp, esum, ctx, aout);
}